// Round 2
// baseline (117.751 us; speedup 1.0000x reference)
//
#include <hip/hip_runtime.h>

#define NGRID 64
#define NEL (NGRID*NGRID*NGRID)
#define NDOF (3*NEL)
#define IDX(i,j,k) ((((i)*64 + (j)) * 64) + (k))

// Pass 1: per-element type code from binarized rho at the 8 corners.
// bit = di*4 + dj*2 + dk  (typeFilter = 2^arange(8).reshape(2,2,2))
__global__ __launch_bounds__(256) void fe_type_kernel(
    const float* __restrict__ rho, unsigned char* __restrict__ types)
{
    int e = blockIdx.x * blockDim.x + threadIdx.x;
    int k = e & 63, j = (e >> 6) & 63, i = (e >> 12) & 63;
    int i1 = (i + 1) & 63, j1 = (j + 1) & 63, k1 = (k + 1) & 63;
    int t = 0;
    t |= (rho[IDX(i,  j,  k )] > 0.5f ? 1 : 0) << 0;
    t |= (rho[IDX(i1, j,  k )] > 0.5f ? 1 : 0) << 4;
    t |= (rho[IDX(i,  j1, k )] > 0.5f ? 1 : 0) << 2;
    t |= (rho[IDX(i1, j1, k )] > 0.5f ? 1 : 0) << 6;
    t |= (rho[IDX(i,  j,  k1)] > 0.5f ? 1 : 0) << 1;
    t |= (rho[IDX(i1, j,  k1)] > 0.5f ? 1 : 0) << 5;
    t |= (rho[IDX(i,  j1, k1)] > 0.5f ? 1 : 0) << 3;
    t |= (rho[IDX(i1, j1, k1)] > 0.5f ? 1 : 0) << 7;
    types[e] = (unsigned char)t;
}

// Pass 2: gather formulation — one thread per NODE, no atomics.
// Node n is local corner c of element e_c = n - OFFSETS[c]; that element
// contributes rows 3c..3c+2 of filters[type(e_c)] . Ue(e_c) to out[3n..3n+2].
__global__ __launch_bounds__(256) void fe_gather_kernel(
    const float* __restrict__ U,
    const unsigned char* __restrict__ types,
    const float* __restrict__ filters,
    float* __restrict__ out)
{
    int n = blockIdx.x * blockDim.x + threadIdx.x;
    int k = n & 63, j = (n >> 6) & 63, i = (n >> 12) & 63;

    // OFFSETS order: (di,dj,dk) per corner slot c
    const int DI[8] = {0,1,0,1,0,1,0,1};
    const int DJ[8] = {0,0,1,1,0,0,1,1};
    const int DK[8] = {0,0,0,0,1,1,1,1};

    float acc0 = 0.0f, acc1 = 0.0f, acc2 = 0.0f;

    #pragma unroll
    for (int c = 0; c < 8; ++c) {
        int ei = (i - DI[c]) & 63;
        int ej = (j - DJ[c]) & 63;
        int ek = (k - DK[c]) & 63;
        int e  = IDX(ei, ej, ek);
        int t  = types[e];

        int ei1 = (ei + 1) & 63, ej1 = (ej + 1) & 63, ek1 = (ek + 1) & 63;
        int nodes[8];
        nodes[0] = IDX(ei,  ej,  ek );
        nodes[1] = IDX(ei1, ej,  ek );
        nodes[2] = IDX(ei,  ej1, ek );
        nodes[3] = IDX(ei1, ej1, ek );
        nodes[4] = IDX(ei,  ej,  ek1);
        nodes[5] = IDX(ei1, ej,  ek1);
        nodes[6] = IDX(ei,  ej1, ek1);
        nodes[7] = IDX(ei1, ej1, ek1);

        float Ue[24];
        #pragma unroll
        for (int m = 0; m < 8; ++m) {
            int b = nodes[m] * 3;
            Ue[3*m + 0] = U[b + 0];
            Ue[3*m + 1] = U[b + 1];
            Ue[3*m + 2] = U[b + 2];
        }

        // rows 3c..3c+2; rows are 96 B, 16B-aligned -> float4 loads
        const float4* __restrict__ Kr = (const float4*)(filters + t * 576 + (3 * c) * 24);
        #pragma unroll
        for (int d = 0; d < 3; ++d) {
            float a = 0.0f;
            #pragma unroll
            for (int q = 0; q < 6; ++q) {
                float4 f = Kr[d * 6 + q];
                a = fmaf(f.x, Ue[4*q + 0], a);
                a = fmaf(f.y, Ue[4*q + 1], a);
                a = fmaf(f.z, Ue[4*q + 2], a);
                a = fmaf(f.w, Ue[4*q + 3], a);
            }
            if      (d == 0) acc0 += a;
            else if (d == 1) acc1 += a;
            else             acc2 += a;
        }
    }

    out[n * 3 + 0] = acc0;
    out[n * 3 + 1] = acc1;
    out[n * 3 + 2] = acc2;
}

extern "C" void kernel_launch(void* const* d_in, const int* in_sizes, int n_in,
                              void* d_out, int out_size, void* d_ws, size_t ws_size,
                              hipStream_t stream) {
    const float* U       = (const float*)d_in[0];
    const float* rho     = (const float*)d_in[1];
    const float* filters = (const float*)d_in[3];
    float* out = (float*)d_out;
    unsigned char* types = (unsigned char*)d_ws;  // NEL bytes of scratch

    fe_type_kernel<<<dim3(NEL / 256), dim3(256), 0, stream>>>(rho, types);
    fe_gather_kernel<<<dim3(NEL / 256), dim3(256), 0, stream>>>(U, types, filters, out);
}

// Round 3
// 58.619 us; speedup vs baseline: 2.0088x; 2.0088x over previous
//
#include <hip/hip_runtime.h>

#define NGRID 64
#define NEL (NGRID*NGRID*NGRID)   /* 262144 */
#define IDX(i,j,k) ((((i)*64 + (j)) * 64) + (k))

// ---- workspace layout (bytes) ----
#define WS_KUE     0                        // NEL*24 f32 = 25165824
#define WS_SORTED  (NEL*24*4)               // NEL i32   = 1048576
#define WS_TYPES   (WS_SORTED + NEL*4)      // NEL u8    = 262144
#define WS_BHIST   (WS_TYPES + NEL)         // 256*256 i32 (hist[t*256+b])
#define WS_BINTOT  (WS_BHIST + 256*256*4)   // 256 i32
#define WS_NEEDED  (size_t)(WS_BINTOT + 256*4)

__device__ __forceinline__ int type_of(const float* __restrict__ rho, int i, int j, int k) {
    int i1 = (i + 1) & 63, j1 = (j + 1) & 63, k1 = (k + 1) & 63;
    // typeFilter[di][dj][dk] = 2^(di*4 + dj*2 + dk); OFFSETS order -> bits {0,4,2,6,1,5,3,7}
    int t = 0;
    t |= (rho[IDX(i,  j,  k )] > 0.5f ? 1 : 0) << 0;
    t |= (rho[IDX(i1, j,  k )] > 0.5f ? 1 : 0) << 4;
    t |= (rho[IDX(i,  j1, k )] > 0.5f ? 1 : 0) << 2;
    t |= (rho[IDX(i1, j1, k )] > 0.5f ? 1 : 0) << 6;
    t |= (rho[IDX(i,  j,  k1)] > 0.5f ? 1 : 0) << 1;
    t |= (rho[IDX(i1, j,  k1)] > 0.5f ? 1 : 0) << 5;
    t |= (rho[IDX(i,  j1, k1)] > 0.5f ? 1 : 0) << 3;
    t |= (rho[IDX(i1, j1, k1)] > 0.5f ? 1 : 0) << 7;
    return t;
}

// K1: types + per-block histogram. 256 blocks x 1024 threads, one element each.
__global__ __launch_bounds__(1024) void k1_types_hist(
    const float* __restrict__ rho, unsigned char* __restrict__ types, int* __restrict__ bhist)
{
    __shared__ int lh[256];
    int tid = threadIdx.x;
    if (tid < 256) lh[tid] = 0;
    __syncthreads();
    int e = blockIdx.x * 1024 + tid;
    int k = e & 63, j = (e >> 6) & 63, i = (e >> 12) & 63;
    int t = type_of(rho, i, j, k);
    types[e] = (unsigned char)t;
    atomicAdd(&lh[t], 1);
    __syncthreads();
    if (tid < 256) bhist[tid * 256 + blockIdx.x] = lh[tid];
}

// K2: per type T, exclusive-scan hist over the 256 blocks; emit per-type total.
__global__ __launch_bounds__(256) void k2_scan(int* __restrict__ bhist, int* __restrict__ bintot)
{
    __shared__ int s[256];
    int T = blockIdx.x, tid = threadIdx.x;
    int v = bhist[T * 256 + tid];
    s[tid] = v;
    __syncthreads();
    #pragma unroll
    for (int off = 1; off < 256; off <<= 1) {
        int tmp = (tid >= off) ? s[tid - off] : 0;
        __syncthreads();
        s[tid] += tmp;
        __syncthreads();
    }
    bhist[T * 256 + tid] = s[tid] - v;          // exclusive over blocks, within type
    if (tid == 255) bintot[T] = s[255];
}

// K3: scatter element ids into type-grouped order. Same geometry as K1.
__global__ __launch_bounds__(1024) void k3_scatter(
    const unsigned char* __restrict__ types, const int* __restrict__ bhist,
    const int* __restrict__ bintot, int* __restrict__ sorted)
{
    __shared__ int lh[256];
    __shared__ int bstart[256];
    int tid = threadIdx.x;
    if (tid < 256) { lh[tid] = 0; bstart[tid] = bintot[tid]; }
    __syncthreads();
    #pragma unroll
    for (int off = 1; off < 256; off <<= 1) {
        int tmp = 0;
        if (tid < 256 && tid >= off) tmp = bstart[tid - off];
        __syncthreads();
        if (tid < 256) bstart[tid] += tmp;       // inclusive scan of totals
        __syncthreads();
    }
    int e = blockIdx.x * 1024 + tid;
    int t = types[e];
    int lrank = atomicAdd(&lh[t], 1);            // within-(block,type) rank
    int pos = (bstart[t] - bintot[t]) + bhist[t * 256 + blockIdx.x] + lrank;
    sorted[pos] = e;
}

// K4: per sorted element: gather Ue, 24x24 matvec (wave-uniform filter), store KUe.
__global__ __launch_bounds__(256) void k4_apply(
    const float* __restrict__ U, const float* __restrict__ filters,
    const int* __restrict__ sorted, const unsigned char* __restrict__ types,
    float* __restrict__ KUe)
{
    int p = blockIdx.x * 256 + threadIdx.x;
    int e = sorted[p];
    int t = types[e];
    int k = e & 63, j = (e >> 6) & 63, i = (e >> 12) & 63;
    int i1 = (i + 1) & 63, j1 = (j + 1) & 63, k1 = (k + 1) & 63;

    int nodes[8];
    nodes[0] = IDX(i,  j,  k );
    nodes[1] = IDX(i1, j,  k );
    nodes[2] = IDX(i,  j1, k );
    nodes[3] = IDX(i1, j1, k );
    nodes[4] = IDX(i,  j,  k1);
    nodes[5] = IDX(i1, j,  k1);
    nodes[6] = IDX(i,  j1, k1);
    nodes[7] = IDX(i1, j1, k1);

    float Ue[24];
    #pragma unroll
    for (int m = 0; m < 8; ++m) {
        int b = nodes[m] * 3;
        Ue[3*m + 0] = U[b + 0];
        Ue[3*m + 1] = U[b + 1];
        Ue[3*m + 2] = U[b + 2];
    }

    const float4* __restrict__ Kr = (const float4*)(filters + t * 576);
    float4 o[6];
    #pragma unroll
    for (int r = 0; r < 24; ++r) {
        float a = 0.0f;
        #pragma unroll
        for (int q = 0; q < 6; ++q) {
            float4 f = Kr[r * 6 + q];
            a = fmaf(f.x, Ue[4*q + 0], a);
            a = fmaf(f.y, Ue[4*q + 1], a);
            a = fmaf(f.z, Ue[4*q + 2], a);
            a = fmaf(f.w, Ue[4*q + 3], a);
        }
        ((float*)o)[r] = a;
    }

    float4* __restrict__ dst = (float4*)(KUe + (size_t)e * 24);  // 96B-aligned
    #pragma unroll
    for (int q = 0; q < 6; ++q) dst[q] = o[q];
}

// K5: per node, sum 3-row slices from 8 incident elements. No atomics.
__global__ __launch_bounds__(256) void k5_gather(
    const float* __restrict__ KUe, float* __restrict__ out)
{
    int n = blockIdx.x * 256 + threadIdx.x;
    int k = n & 63, j = (n >> 6) & 63, i = (n >> 12) & 63;

    const int DI[8] = {0,1,0,1,0,1,0,1};
    const int DJ[8] = {0,0,1,1,0,0,1,1};
    const int DK[8] = {0,0,0,0,1,1,1,1};

    float a0 = 0.f, a1 = 0.f, a2 = 0.f;
    #pragma unroll
    for (int c = 0; c < 8; ++c) {
        int ei = (i - DI[c]) & 63;
        int ej = (j - DJ[c]) & 63;
        int ek = (k - DK[c]) & 63;
        const float* __restrict__ src = KUe + (size_t)IDX(ei, ej, ek) * 24 + 3 * c;
        a0 += src[0];
        a1 += src[1];
        a2 += src[2];
    }
    out[n*3 + 0] = a0;
    out[n*3 + 1] = a1;
    out[n*3 + 2] = a2;
}

// Fallback (ws too small): round-1 atomic scatter kernel.
__global__ __launch_bounds__(256) void fe_apply_atomic(
    const float* __restrict__ U, const float* __restrict__ rho,
    const float* __restrict__ filters, float* __restrict__ out)
{
    int e = blockIdx.x * blockDim.x + threadIdx.x;
    int k = e & 63, j = (e >> 6) & 63, i = (e >> 12) & 63;
    int i1 = (i + 1) & 63, j1 = (j + 1) & 63, k1 = (k + 1) & 63;
    int nodes[8];
    nodes[0]=IDX(i,j,k);   nodes[1]=IDX(i1,j,k);   nodes[2]=IDX(i,j1,k);   nodes[3]=IDX(i1,j1,k);
    nodes[4]=IDX(i,j,k1);  nodes[5]=IDX(i1,j,k1);  nodes[6]=IDX(i,j1,k1);  nodes[7]=IDX(i1,j1,k1);
    int t = type_of(rho, i, j, k);
    float Ue[24];
    #pragma unroll
    for (int m = 0; m < 8; ++m) {
        int b = nodes[m] * 3;
        Ue[3*m+0]=U[b+0]; Ue[3*m+1]=U[b+1]; Ue[3*m+2]=U[b+2];
    }
    const float4* Kr = (const float4*)(filters + t * 576);
    #pragma unroll
    for (int r = 0; r < 24; ++r) {
        float a = 0.f;
        #pragma unroll
        for (int q = 0; q < 6; ++q) {
            float4 f = Kr[r*6+q];
            a = fmaf(f.x,Ue[4*q+0],a); a = fmaf(f.y,Ue[4*q+1],a);
            a = fmaf(f.z,Ue[4*q+2],a); a = fmaf(f.w,Ue[4*q+3],a);
        }
        atomicAdd(&out[nodes[r/3]*3 + (r%3)], a);
    }
}

extern "C" void kernel_launch(void* const* d_in, const int* in_sizes, int n_in,
                              void* d_out, int out_size, void* d_ws, size_t ws_size,
                              hipStream_t stream) {
    const float* U       = (const float*)d_in[0];
    const float* rho     = (const float*)d_in[1];
    const float* filters = (const float*)d_in[3];
    float* out = (float*)d_out;

    if (ws_size < WS_NEEDED) {
        hipMemsetAsync(out, 0, (size_t)out_size * sizeof(float), stream);
        fe_apply_atomic<<<dim3(NEL/256), dim3(256), 0, stream>>>(U, rho, filters, out);
        return;
    }

    char* ws = (char*)d_ws;
    float*         KUe    = (float*)(ws + WS_KUE);
    int*           sorted = (int*)(ws + WS_SORTED);
    unsigned char* types  = (unsigned char*)(ws + WS_TYPES);
    int*           bhist  = (int*)(ws + WS_BHIST);
    int*           bintot = (int*)(ws + WS_BINTOT);

    k1_types_hist<<<dim3(256),  dim3(1024), 0, stream>>>(rho, types, bhist);
    k2_scan      <<<dim3(256),  dim3(256),  0, stream>>>(bhist, bintot);
    k3_scatter   <<<dim3(256),  dim3(1024), 0, stream>>>(types, bhist, bintot, sorted);
    k4_apply     <<<dim3(1024), dim3(256),  0, stream>>>(U, filters, sorted, types, KUe);
    k5_gather    <<<dim3(1024), dim3(256),  0, stream>>>(KUe, out);
}